// Round 14
// baseline (168.028 us; speedup 1.0000x reference)
//
#include <hip/hip_runtime.h>

// Problem constants (match reference)
#define BQ 512
#define AQ 32
#define DQ 256
#define NQ (BQ * AQ)      // 16384 nodes
#define EQ 1048576        // edges
#define THR 0.5f
#define EPSF 1e-5f
#define DEG_STRIDE 160    // per-target list cap; deg ~ Binom(E,1/N) mean 64, +12 sigma
#define BIN_TGTS 64       // targets per bin
#define NBINS (NQ / BIN_TGTS)          // 256
#define NBLK_P 256        // partition blocks
#define EPB (EQ / NBLK_P) // 4096 edges per partition block

typedef __attribute__((ext_vector_type(8))) short bf16x8;
typedef __attribute__((ext_vector_type(4))) float f32x4;

// fp32 -> bf16 round-to-nearest-even (finite inputs)
__device__ __forceinline__ unsigned short f2bf(float f) {
    unsigned int u = __float_as_uint(f);
    return (unsigned short)((u + 0x7FFFu + ((u >> 16) & 1u)) >> 16);
}
__device__ __forceinline__ float bf2f(unsigned short h) {
    return __uint_as_float((unsigned int)h << 16);
}

// ---------------------------------------------------------------------------
// Dispatch 1 — the two INDEPENDENT heavy slices, finally co-scheduled:
//  blocks [0,256):    PRIVATE partition (EXACT R13 body): LDS-sort 4096 edges
//                     by bin -> contiguous exclusively-owned 16KB burst +
//                     coalesced cntT/offT rows. No global atomics, no memset.
//  blocks [256,512):  bf16x3 split MFMA GEMM with INLINE W conversion: stages
//                     W fp32 directly per K-slab (32 coalesced 256B row reads
//                     of the L2-resident 256KB W, f2bf hi/lo in registers,
//                     same LDS layout as the old Wt staging -> bit-identical
//                     xwb). Removes the wt dispatch AND the dead part->gemm
//                     dependency: serial front shrinks from part+gemm to
//                     max(part,gemm).
// ---------------------------------------------------------------------------
__global__ __launch_bounds__(256) void k_part_gemm(
        const float* __restrict__ W, const float* __restrict__ Xp,
        unsigned short* __restrict__ xwb,
        const int* __restrict__ src, const int* __restrict__ tgt,
        int* __restrict__ cntT, int* __restrict__ offT,
        unsigned int* __restrict__ binned) {
    __shared__ unsigned short bs[2][256 * 40];   // 40 KB (gemm); part aliases 19 KB
    int tid = threadIdx.x;
    if (blockIdx.x < 256) {
        // ---- private partition (aliased LDS) ----
        unsigned int* buf = (unsigned int*)&bs[0][0];            // 16 KB
        int* hist = (int*)((char*)bs + 16 * 1024);               // 1 KB
        int* sdat = hist + NBINS;                                // 1 KB
        int* cur  = sdat + NBINS;                                // 1 KB
        int blk = blockIdx.x;
        hist[tid] = 0;
        __syncthreads();
        int base = blk * EPB;
        int t[16], s[16];
        #pragma unroll
        for (int i = 0; i < 16; i++) {
            int e = base + i * 256 + tid;
            t[i] = tgt[e];
            s[i] = src[e];
            atomicAdd(&hist[t[i] >> 6], 1);
        }
        __syncthreads();
        // exclusive prefix over the 256 bins (Hillis-Steele in LDS)
        int v = hist[tid];
        sdat[tid] = v;
        __syncthreads();
        #pragma unroll
        for (int off = 1; off < 256; off <<= 1) {
            int add = (tid >= off) ? sdat[tid - off] : 0;
            __syncthreads();
            sdat[tid] += add;
            __syncthreads();
        }
        int excl = sdat[tid] - v;
        cur[tid] = excl;
        cntT[blk * NBINS + tid] = v;      // [blk][bin]: private coalesced row
        offT[blk * NBINS + tid] = excl;
        __syncthreads();
        // LDS scatter into bin-sorted order
        #pragma unroll
        for (int i = 0; i < 16; i++) {
            int pos = atomicAdd(&cur[t[i] >> 6], 1);
            buf[pos] = ((unsigned int)t[i] << 14) | (unsigned int)s[i];
        }
        __syncthreads();
        // stream out: contiguous 16KB, exclusively-owned region
        unsigned int* g = binned + (size_t)blk * EPB;
        #pragma unroll
        for (int i = 0; i < 16; i++) g[i * 256 + tid] = buf[i * 256 + tid];
        return;
    }
    // ---- bf16x3 split MFMA GEMM, LDS-staged B with inline W conversion ----
    int wave = tid >> 6;
    int lane = tid & 63;
    int col = lane & 15;
    int quad = lane >> 4;
    int mbase = (blockIdx.x - 256) * 64 + wave * 16;
    int m = mbase + col;

    const float* arow = Xp + (size_t)m * DQ;

    f32x4 acc[16];
    f32x4 zero = {0.f, 0.f, 0.f, 0.f};
    #pragma unroll
    for (int i = 0; i < 16; i++) acc[i] = zero;

    for (int k0 = 0; k0 < DQ; k0 += 32) {
        __syncthreads();              // previous slab fully consumed
        {
            // stage: thread tid produces row n=tid, cols [k0,k0+32), both
            // planes, converting from W fp32 on the fly. Global reads are
            // coalesced per kk (lanes read consecutive n: 256B/wave).
            unsigned int hw[16], lw[16];
            #pragma unroll
            for (int p = 0; p < 16; p++) {
                float w0 = W[(size_t)(k0 + 2 * p) * DQ + tid];
                float w1 = W[(size_t)(k0 + 2 * p + 1) * DQ + tid];
                unsigned short h0 = f2bf(w0);
                unsigned short h1 = f2bf(w1);
                hw[p] = (unsigned int)h0 | ((unsigned int)h1 << 16);
                unsigned short l0 = f2bf(w0 - bf2f(h0));
                unsigned short l1 = f2bf(w1 - bf2f(h1));
                lw[p] = (unsigned int)l0 | ((unsigned int)l1 << 16);
            }
            unsigned int* lh = (unsigned int*)&bs[0][tid * 40];
            unsigned int* ll = (unsigned int*)&bs[1][tid * 40];
            #pragma unroll
            for (int u = 0; u < 16; u++) { lh[u] = hw[u]; ll[u] = lw[u]; }
        }
        __syncthreads();

        int kq = k0 + quad * 8;
        float4 a0 = *(const float4*)(arow + kq);
        float4 a1 = *(const float4*)(arow + kq + 4);
        float av[8] = {a0.x, a0.y, a0.z, a0.w, a1.x, a1.y, a1.z, a1.w};
        bf16x8 ah, al;
        #pragma unroll
        for (int j = 0; j < 8; j++) {
            unsigned short h = f2bf(av[j]);
            ah[j] = (short)h;
            al[j] = (short)f2bf(av[j] - bf2f(h));
        }
        #pragma unroll
        for (int nt = 0; nt < 16; nt++) {
            int n = nt * 16 + col;
            bf16x8 bh = *(const bf16x8*)&bs[0][n * 40 + quad * 8];
            bf16x8 bl = *(const bf16x8*)&bs[1][n * 40 + quad * 8];
            acc[nt] = __builtin_amdgcn_mfma_f32_16x16x32_bf16(ah, bh, acc[nt], 0, 0, 0);
            acc[nt] = __builtin_amdgcn_mfma_f32_16x16x32_bf16(al, bh, acc[nt], 0, 0, 0);
            acc[nt] = __builtin_amdgcn_mfma_f32_16x16x32_bf16(ah, bl, acc[nt], 0, 0, 0);
        }
    }

    #pragma unroll
    for (int nt = 0; nt < 16; nt++) {
        #pragma unroll
        for (int r = 0; r < 4; r++) {
            xwb[(size_t)(mbase + quad * 4 + r) * DQ + nt * 16 + col] =
                f2bf(acc[nt][r]);
        }
    }
}

// ---------------------------------------------------------------------------
// Dispatch 2: BUCKET BUILD (EXACT R13 slice, standalone): per bin, drain the
// 256 private sub-lists into per-target LDS lists -> coalesced 20KB bucket
// write + cnt + dinv. ~8-12 us exposed.
// ---------------------------------------------------------------------------
__global__ __launch_bounds__(256) void k_bucket(
        const int* __restrict__ cntT, const int* __restrict__ offT,
        const unsigned int* __restrict__ binned,
        unsigned short* __restrict__ bucket, int* __restrict__ cnt,
        float* __restrict__ dinv) {
    __shared__ unsigned short lbuck[BIN_TGTS * DEG_STRIDE];  // 20 KB
    __shared__ int lcnt[BIN_TGTS];
    int tid = threadIdx.x;
    int b = blockIdx.x;
    if (tid < BIN_TGTS) lcnt[tid] = 0;
    __syncthreads();
    // thread tid drains partition-block tid's sub-list for bin b
    int c = cntT[tid * NBINS + b];
    int o = offT[tid * NBINS + b];
    const unsigned int* e = binned + (size_t)tid * EPB + o;
    for (int j = 0; j < c; j++) {
        unsigned int ed = e[j];
        int tl = (int)(ed >> 14) & 63;
        int pos = atomicAdd(&lcnt[tl], 1);
        if (pos < DEG_STRIDE)
            lbuck[tl * DEG_STRIDE + pos] = (unsigned short)(ed & 0x3FFFu);
    }
    __syncthreads();
    const unsigned int* lb32 = (const unsigned int*)lbuck;   // 5120 uints
    unsigned int* gb32 = (unsigned int*)(bucket + (size_t)b * BIN_TGTS * DEG_STRIDE);
    #pragma unroll
    for (int i = 0; i < 20; i++) gb32[i * 256 + tid] = lb32[i * 256 + tid];
    if (tid < BIN_TGTS) {
        int cc = lcnt[tid];
        cnt[b * BIN_TGTS + tid] = cc;
        dinv[b * BIN_TGTS + tid] = rsqrtf((float)(cc + 1));
    }
}

// ---------------------------------------------------------------------------
// Fused aggregation + scores — EXACT ROUND-0/13 BODY (65us proven): gather
// reads pre-built bucket rows coalesced (2B/lane prefetch + shfl broadcast),
// then the score math. Byte-identical numerics.
// ---------------------------------------------------------------------------
__global__ __launch_bounds__(512) void k_agg_scores(
        const unsigned int* __restrict__ xwb,
        const int* __restrict__ cnt,
        const unsigned short* __restrict__ bucket,
        const float* __restrict__ dinv,
        const float* __restrict__ bias,
        float* __restrict__ out,      // Xo [NQ*DQ]
        float* __restrict__ mask) {   // [BQ*AQ*AQ]
    __shared__ float xs[AQ][DQ + 4];   // 33 KB; rows 1040B = 65x16B aligned
    __shared__ float sq[AQ];
    __shared__ float sc[AQ][AQ + 1];
    __shared__ float rmin[AQ], rmax[AQ];

    int tid = threadIdx.x;
    int wave = tid >> 6;              // 0..7
    int lane = tid & 63;
    int bq = blockIdx.x;              // batch clip
    const uint2* xw2 = (const uint2*)xwb;

    float4 bv = ((const float4*)bias)[lane];

    // ---- phase 1: gather 4 targets per wave ----
    #pragma unroll 1
    for (int i = 0; i < 4; i++) {
        int a = wave * 4 + i;         // actor 0..31
        int t = bq * AQ + a;
        float dt = dinv[t];
        float c0 = dt * dt;
        uint2 sp = xw2[(size_t)t * 64 + lane];
        float4 acc;
        acc.x = __uint_as_float(sp.x << 16) * c0;
        acc.y = __uint_as_float(sp.x & 0xFFFF0000u) * c0;
        acc.z = __uint_as_float(sp.y << 16) * c0;
        acc.w = __uint_as_float(sp.y & 0xFFFF0000u) * c0;

        const unsigned short* brow = bucket + (size_t)t * DEG_STRIDE;
        int num = cnt[t];
        if (num > DEG_STRIDE) num = DEG_STRIDE;
        for (int k0 = 0; k0 < num; k0 += 64) {
            int rem = num - k0;
            int n = rem < 64 ? rem : 64;
            int idx = k0 + (lane < n ? lane : 0);
            int e = (int)brow[idx];               // coalesced 2B/lane prefetch
            float cl = (lane < n) ? dinv[e] * dt : 0.f;
            int n8 = (n + 7) & ~7;
            for (int j0 = 0; j0 < n8; j0 += 8) {
                #pragma unroll
                for (int jj = 0; jj < 8; jj++) {
                    int j = j0 + jj;
                    int s = __shfl(e, j);
                    float c = __shfl(cl, j);
                    uint2 p = xw2[(size_t)s * 64 + lane];
                    acc.x += __uint_as_float(p.x << 16) * c;
                    acc.y += __uint_as_float(p.x & 0xFFFF0000u) * c;
                    acc.z += __uint_as_float(p.y << 16) * c;
                    acc.w += __uint_as_float(p.y & 0xFFFF0000u) * c;
                }
            }
        }

        acc.x += bv.x; acc.y += bv.y; acc.z += bv.z; acc.w += bv.w;
        ((float4*)out)[(size_t)t * 64 + lane] = acc;
        *(float4*)&xs[a][lane * 4] = acc;
    }
    __syncthreads();

    // ---- phase 2: scores (identical math to round 0) ----
    if (tid < AQ) {
        const float4* xi = (const float4*)xs[tid];
        float s = 0.f;
        #pragma unroll 8
        for (int dd = 0; dd < DQ / 4; dd++) {
            float4 a = xi[dd];
            s += a.x * a.x + a.y * a.y + a.z * a.z + a.w * a.w;
        }
        sq[tid] = s;
    }
    __syncthreads();

    {
        int p0 = tid * 2;             // 2 pairs per thread (1024 pairs)
        int i = p0 >> 5;
        int j0 = p0 & 31;
        const float4* xi = (const float4*)xs[i];
        float g[2] = {0.f, 0.f};
        for (int dd = 0; dd < DQ / 4; dd += 8) {
            float4 ar[8];
            #pragma unroll
            for (int u = 0; u < 8; u++) ar[u] = xi[dd + u];
            #pragma unroll
            for (int q = 0; q < 2; q++) {
                const float4* xj = (const float4*)xs[j0 + q];
                float gq = 0.f;
                #pragma unroll
                for (int u = 0; u < 8; u++) {
                    float4 b = xj[dd + u];
                    gq += ar[u].x * b.x + ar[u].y * b.y +
                          ar[u].z * b.z + ar[u].w * b.w;
                }
                g[q] += gq;
            }
        }
        #pragma unroll
        for (int q = 0; q < 2; q++) {
            sc[i][j0 + q] = sq[i] - 2.f * g[q] + sq[j0 + q];
        }
    }
    __syncthreads();

    if (tid < AQ) {
        float mn = sc[tid][0], mx = sc[tid][0];
        for (int j = 1; j < AQ; j++) {
            float v = sc[tid][j];
            mn = fminf(mn, v);
            mx = fmaxf(mx, v);
        }
        rmin[tid] = mn;
        rmax[tid] = mx;
    }
    __syncthreads();

    {
        float* mb = mask + (size_t)bq * AQ * AQ;
        int p0 = tid * 2;
        int i = p0 >> 5, j0 = p0 & 31;
        float inv = 1.0f / (rmax[i] - rmin[i] + EPSF);
        float2 mv;
        mv.x = ((sc[i][j0 + 0] - rmin[i]) * inv > THR) ? 1.0f : 0.0f;
        mv.y = ((sc[i][j0 + 1] - rmin[i]) * inv > THR) ? 1.0f : 0.0f;
        ((float2*)mb)[tid] = mv;
    }
}

// ---------------------------------------------------------------------------
extern "C" void kernel_launch(void* const* d_in, const int* in_sizes, int n_in,
                              void* d_out, int out_size, void* d_ws, size_t ws_size,
                              hipStream_t stream) {
    const float* X    = (const float*)d_in[0];   // [B,A,D]
    const int*   ei   = (const int*)d_in[1];     // [2,E]
    const float* W    = (const float*)d_in[2];   // [D,D]
    const float* bias = (const float*)d_in[3];   // [D]
    float* out = (float*)d_out;                  // [N*D] Xo  ++  [B*A*A] mask

    char* ws = (char*)d_ws;
    unsigned short* xwb = (unsigned short*)ws;                              // 8 MB
    unsigned int* binned = (unsigned int*)(ws + (size_t)NQ * DQ * 2);       // 4 MB
    unsigned short* bucket = (unsigned short*)(binned + (size_t)NBLK_P * EPB); // 5.25 MB
    float* dinv = (float*)(bucket + (size_t)NQ * DEG_STRIDE);               // 64 KB
    int* cnt = (int*)(dinv + NQ);                                           // 64 KB
    int* cntT = cnt + NQ;                                                   // 256 KB
    int* offT = cntT + NBLK_P * NBINS;                                      // 256 KB

    const int* src = ei;
    const int* tgt = ei + EQ;

    k_part_gemm<<<512, 256, 0, stream>>>(W, X, xwb, src, tgt, cntT, offT, binned);
    k_bucket<<<NBINS, 256, 0, stream>>>(cntT, offT, binned, bucket, cnt, dinv);
    k_agg_scores<<<BQ, 512, 0, stream>>>((const unsigned int*)xwb, cnt, bucket,
                                         dinv, bias, out,
                                         out + (size_t)NQ * DQ);
}

// Round 16
// 163.009 us; speedup vs baseline: 1.0308x; 1.0308x over previous
//
#include <hip/hip_runtime.h>

// Problem constants (match reference)
#define BQ 512
#define AQ 32
#define DQ 256
#define NQ (BQ * AQ)      // 16384 nodes
#define EQ 1048576        // edges
#define THR 0.5f
#define EPSF 1e-5f
#define DEG_STRIDE 160    // per-target list cap; deg ~ Binom(E,1/N) mean 64, +12 sigma
#define BIN_TGTS 64       // targets per bin
#define NBINS (NQ / BIN_TGTS)          // 256
#define NBLK_P 256        // partition blocks
#define EPB (EQ / NBLK_P) // 4096 edges per partition block

typedef __attribute__((ext_vector_type(8))) short bf16x8;
typedef __attribute__((ext_vector_type(4))) float f32x4;

// fp32 -> bf16 round-to-nearest-even (finite inputs)
__device__ __forceinline__ unsigned short f2bf(float f) {
    unsigned int u = __float_as_uint(f);
    return (unsigned short)((u + 0x7FFFu + ((u >> 16) & 1u)) >> 16);
}
__device__ __forceinline__ float bf2f(unsigned short h) {
    return __uint_as_float((unsigned int)h << 16);
}

// ---------------------------------------------------------------------------
// Dispatch 1 (R13 champion, byte-identical):
//  blocks [0,256):    W [K,N] fp32 -> Wt hi/lo [N,K] bf16 split
//  blocks [256,512):  PRIVATE partition: LDS-sort 4096 edges by bin ->
//                     one contiguous exclusively-owned 16KB burst to
//                     binned[blk][4096] + coalesced cntT/offT[blk][bin] rows.
//                     No global atomics, no memset, no shared cache lines.
// ---------------------------------------------------------------------------
__global__ __launch_bounds__(256) void k_wt_part(
        const float* __restrict__ W, unsigned short* __restrict__ Wt,
        const int* __restrict__ src, const int* __restrict__ tgt,
        int* __restrict__ cntT, int* __restrict__ offT,
        unsigned int* __restrict__ binned) {
    __shared__ unsigned int buf[EPB];   // 16 KB
    __shared__ int hist[NBINS];
    __shared__ int sdat[NBINS];
    __shared__ int cur[NBINS];
    int tid = threadIdx.x;
    if (blockIdx.x < 256) {
        int idx = blockIdx.x * 256 + tid;       // covers DQ*DQ
        int n = idx >> 8;
        int k = idx & 255;
        float w = W[k * DQ + n];
        unsigned short h = f2bf(w);
        Wt[idx] = h;                            // hi plane
        Wt[DQ * DQ + idx] = f2bf(w - bf2f(h));  // lo plane
        return;
    }
    int blk = blockIdx.x - 256;
    hist[tid] = 0;
    __syncthreads();
    int base = blk * EPB;
    int t[16], s[16];
    #pragma unroll
    for (int i = 0; i < 16; i++) {
        int e = base + i * 256 + tid;
        t[i] = tgt[e];
        s[i] = src[e];
        atomicAdd(&hist[t[i] >> 6], 1);
    }
    __syncthreads();
    // exclusive prefix over the 256 bins (Hillis-Steele in LDS)
    int v = hist[tid];
    sdat[tid] = v;
    __syncthreads();
    #pragma unroll
    for (int off = 1; off < 256; off <<= 1) {
        int add = (tid >= off) ? sdat[tid - off] : 0;
        __syncthreads();
        sdat[tid] += add;
        __syncthreads();
    }
    int excl = sdat[tid] - v;
    cur[tid] = excl;
    cntT[blk * NBINS + tid] = v;      // [blk][bin]: private coalesced row
    offT[blk * NBINS + tid] = excl;
    __syncthreads();
    // LDS scatter into bin-sorted order
    #pragma unroll
    for (int i = 0; i < 16; i++) {
        int pos = atomicAdd(&cur[t[i] >> 6], 1);
        buf[pos] = ((unsigned int)t[i] << 14) | (unsigned int)s[i];
    }
    __syncthreads();
    // stream out: contiguous 16KB, exclusively-owned region
    unsigned int* g = binned + (size_t)blk * EPB;
    #pragma unroll
    for (int i = 0; i < 16; i++) g[i * 256 + tid] = buf[i * 256 + tid];
}

// ---------------------------------------------------------------------------
// Dispatch 2 (R13 champion, byte-identical):
//  blocks [0,256):    bf16x3 split MFMA GEMM, LDS-staged B (bit-identical xwb)
//  blocks [256,512):  bucket build from the private per-(blk,bin) sub-lists:
//                     LDS per-target scatter -> coalesced 20KB bucket write
//                     + cnt + dinv. Hidden under the GEMM shadow.
// ---------------------------------------------------------------------------
__global__ __launch_bounds__(256) void k_gemm_bucket(
        const float* __restrict__ Xp, const unsigned short* __restrict__ Wt,
        unsigned short* __restrict__ xwb,
        const int* __restrict__ cntT, const int* __restrict__ offT,
        const unsigned int* __restrict__ binned,
        unsigned short* __restrict__ bucket, int* __restrict__ cnt,
        float* __restrict__ dinv) {
    __shared__ unsigned short bs[2][256 * 40];   // 40 KB (gemm); bucket aliases 20KB
    __shared__ int lcnt[BIN_TGTS];
    int tid = threadIdx.x;
    if (blockIdx.x >= 256) {
        // ---- bucket build for bin b ----
        unsigned short* lbuck = &bs[0][0];       // 64 * DEG_STRIDE shorts = 20 KB
        int b = blockIdx.x - 256;
        if (tid < BIN_TGTS) lcnt[tid] = 0;
        __syncthreads();
        // thread tid drains partition-block tid's sub-list for bin b
        int c = cntT[tid * NBINS + b];
        int o = offT[tid * NBINS + b];
        const unsigned int* e = binned + (size_t)tid * EPB + o;
        for (int j = 0; j < c; j++) {
            unsigned int ed = e[j];
            int tl = (int)(ed >> 14) & 63;
            int pos = atomicAdd(&lcnt[tl], 1);
            if (pos < DEG_STRIDE)
                lbuck[tl * DEG_STRIDE + pos] = (unsigned short)(ed & 0x3FFFu);
        }
        __syncthreads();
        const unsigned int* lb32 = (const unsigned int*)lbuck;   // 5120 uints
        unsigned int* gb32 = (unsigned int*)(bucket + (size_t)b * BIN_TGTS * DEG_STRIDE);
        #pragma unroll
        for (int i = 0; i < 20; i++) gb32[i * 256 + tid] = lb32[i * 256 + tid];
        if (tid < BIN_TGTS) {
            int cc = lcnt[tid];
            cnt[b * BIN_TGTS + tid] = cc;
            dinv[b * BIN_TGTS + tid] = rsqrtf((float)(cc + 1));
        }
        return;
    }
    // ---- bf16x3 split MFMA GEMM, LDS-staged B (EXACT round-7 body) ----
    int wave = tid >> 6;
    int lane = tid & 63;
    int col = lane & 15;
    int quad = lane >> 4;
    int mbase = blockIdx.x * 64 + wave * 16;
    int m = mbase + col;

    const float* arow = Xp + (size_t)m * DQ;
    const unsigned short* Wlo = Wt + DQ * DQ;

    f32x4 acc[16];
    f32x4 zero = {0.f, 0.f, 0.f, 0.f};
    #pragma unroll
    for (int i = 0; i < 16; i++) acc[i] = zero;

    for (int k0 = 0; k0 < DQ; k0 += 32) {
        __syncthreads();              // previous slab fully consumed
        {
            const uint4* gh = (const uint4*)(Wt + tid * DQ + k0);   // 64B contig
            const uint4* gl = (const uint4*)(Wlo + tid * DQ + k0);
            uint4* lh = (uint4*)&bs[0][tid * 40];
            uint4* ll = (uint4*)&bs[1][tid * 40];
            #pragma unroll
            for (int u = 0; u < 4; u++) lh[u] = gh[u];
            #pragma unroll
            for (int u = 0; u < 4; u++) ll[u] = gl[u];
        }
        __syncthreads();

        int kq = k0 + quad * 8;
        float4 a0 = *(const float4*)(arow + kq);
        float4 a1 = *(const float4*)(arow + kq + 4);
        float av[8] = {a0.x, a0.y, a0.z, a0.w, a1.x, a1.y, a1.z, a1.w};
        bf16x8 ah, al;
        #pragma unroll
        for (int j = 0; j < 8; j++) {
            unsigned short h = f2bf(av[j]);
            ah[j] = (short)h;
            al[j] = (short)f2bf(av[j] - bf2f(h));
        }
        #pragma unroll
        for (int nt = 0; nt < 16; nt++) {
            int n = nt * 16 + col;
            bf16x8 bh = *(const bf16x8*)&bs[0][n * 40 + quad * 8];
            bf16x8 bl = *(const bf16x8*)&bs[1][n * 40 + quad * 8];
            acc[nt] = __builtin_amdgcn_mfma_f32_16x16x32_bf16(ah, bh, acc[nt], 0, 0, 0);
            acc[nt] = __builtin_amdgcn_mfma_f32_16x16x32_bf16(al, bh, acc[nt], 0, 0, 0);
            acc[nt] = __builtin_amdgcn_mfma_f32_16x16x32_bf16(ah, bl, acc[nt], 0, 0, 0);
        }
    }

    #pragma unroll
    for (int nt = 0; nt < 16; nt++) {
        #pragma unroll
        for (int r = 0; r < 4; r++) {
            xwb[(size_t)(mbase + quad * 4 + r) * DQ + nt * 16 + col] =
                f2bf(acc[nt][r]);
        }
    }
}

// ---------------------------------------------------------------------------
// Fused aggregation + scores — EXACT ROUND-0/13 BODY (64.5us proven): gather
// reads pre-built bucket rows coalesced (2B/lane prefetch + shfl broadcast),
// then the score math. Byte-identical numerics.
// ---------------------------------------------------------------------------
__global__ __launch_bounds__(512) void k_agg_scores(
        const unsigned int* __restrict__ xwb,
        const int* __restrict__ cnt,
        const unsigned short* __restrict__ bucket,
        const float* __restrict__ dinv,
        const float* __restrict__ bias,
        float* __restrict__ out,      // Xo [NQ*DQ]
        float* __restrict__ mask) {   // [BQ*AQ*AQ]
    __shared__ float xs[AQ][DQ + 4];   // 33 KB; rows 1040B = 65x16B aligned
    __shared__ float sq[AQ];
    __shared__ float sc[AQ][AQ + 1];
    __shared__ float rmin[AQ], rmax[AQ];

    int tid = threadIdx.x;
    int wave = tid >> 6;              // 0..7
    int lane = tid & 63;
    int bq = blockIdx.x;              // batch clip
    const uint2* xw2 = (const uint2*)xwb;

    float4 bv = ((const float4*)bias)[lane];

    // ---- phase 1: gather 4 targets per wave ----
    #pragma unroll 1
    for (int i = 0; i < 4; i++) {
        int a = wave * 4 + i;         // actor 0..31
        int t = bq * AQ + a;
        float dt = dinv[t];
        float c0 = dt * dt;
        uint2 sp = xw2[(size_t)t * 64 + lane];
        float4 acc;
        acc.x = __uint_as_float(sp.x << 16) * c0;
        acc.y = __uint_as_float(sp.x & 0xFFFF0000u) * c0;
        acc.z = __uint_as_float(sp.y << 16) * c0;
        acc.w = __uint_as_float(sp.y & 0xFFFF0000u) * c0;

        const unsigned short* brow = bucket + (size_t)t * DEG_STRIDE;
        int num = cnt[t];
        if (num > DEG_STRIDE) num = DEG_STRIDE;
        for (int k0 = 0; k0 < num; k0 += 64) {
            int rem = num - k0;
            int n = rem < 64 ? rem : 64;
            int idx = k0 + (lane < n ? lane : 0);
            int e = (int)brow[idx];               // coalesced 2B/lane prefetch
            float cl = (lane < n) ? dinv[e] * dt : 0.f;
            int n8 = (n + 7) & ~7;
            for (int j0 = 0; j0 < n8; j0 += 8) {
                #pragma unroll
                for (int jj = 0; jj < 8; jj++) {
                    int j = j0 + jj;
                    int s = __shfl(e, j);
                    float c = __shfl(cl, j);
                    uint2 p = xw2[(size_t)s * 64 + lane];
                    acc.x += __uint_as_float(p.x << 16) * c;
                    acc.y += __uint_as_float(p.x & 0xFFFF0000u) * c;
                    acc.z += __uint_as_float(p.y << 16) * c;
                    acc.w += __uint_as_float(p.y & 0xFFFF0000u) * c;
                }
            }
        }

        acc.x += bv.x; acc.y += bv.y; acc.z += bv.z; acc.w += bv.w;
        ((float4*)out)[(size_t)t * 64 + lane] = acc;
        *(float4*)&xs[a][lane * 4] = acc;
    }
    __syncthreads();

    // ---- phase 2: scores (identical math to round 0) ----
    if (tid < AQ) {
        const float4* xi = (const float4*)xs[tid];
        float s = 0.f;
        #pragma unroll 8
        for (int dd = 0; dd < DQ / 4; dd++) {
            float4 a = xi[dd];
            s += a.x * a.x + a.y * a.y + a.z * a.z + a.w * a.w;
        }
        sq[tid] = s;
    }
    __syncthreads();

    {
        int p0 = tid * 2;             // 2 pairs per thread (1024 pairs)
        int i = p0 >> 5;
        int j0 = p0 & 31;
        const float4* xi = (const float4*)xs[i];
        float g[2] = {0.f, 0.f};
        for (int dd = 0; dd < DQ / 4; dd += 8) {
            float4 ar[8];
            #pragma unroll
            for (int u = 0; u < 8; u++) ar[u] = xi[dd + u];
            #pragma unroll
            for (int q = 0; q < 2; q++) {
                const float4* xj = (const float4*)xs[j0 + q];
                float gq = 0.f;
                #pragma unroll
                for (int u = 0; u < 8; u++) {
                    float4 b = xj[dd + u];
                    gq += ar[u].x * b.x + ar[u].y * b.y +
                          ar[u].z * b.z + ar[u].w * b.w;
                }
                g[q] += gq;
            }
        }
        #pragma unroll
        for (int q = 0; q < 2; q++) {
            sc[i][j0 + q] = sq[i] - 2.f * g[q] + sq[j0 + q];
        }
    }
    __syncthreads();

    if (tid < AQ) {
        float mn = sc[tid][0], mx = sc[tid][0];
        for (int j = 1; j < AQ; j++) {
            float v = sc[tid][j];
            mn = fminf(mn, v);
            mx = fmaxf(mx, v);
        }
        rmin[tid] = mn;
        rmax[tid] = mx;
    }
    __syncthreads();

    {
        float* mb = mask + (size_t)bq * AQ * AQ;
        int p0 = tid * 2;
        int i = p0 >> 5, j0 = p0 & 31;
        float inv = 1.0f / (rmax[i] - rmin[i] + EPSF);
        float2 mv;
        mv.x = ((sc[i][j0 + 0] - rmin[i]) * inv > THR) ? 1.0f : 0.0f;
        mv.y = ((sc[i][j0 + 1] - rmin[i]) * inv > THR) ? 1.0f : 0.0f;
        ((float2*)mb)[tid] = mv;
    }
}

// ---------------------------------------------------------------------------
extern "C" void kernel_launch(void* const* d_in, const int* in_sizes, int n_in,
                              void* d_out, int out_size, void* d_ws, size_t ws_size,
                              hipStream_t stream) {
    const float* X    = (const float*)d_in[0];   // [B,A,D]
    const int*   ei   = (const int*)d_in[1];     // [2,E]
    const float* W    = (const float*)d_in[2];   // [D,D]
    const float* bias = (const float*)d_in[3];   // [D]
    float* out = (float*)d_out;                  // [N*D] Xo  ++  [B*A*A] mask

    char* ws = (char*)d_ws;
    unsigned short* xwb = (unsigned short*)ws;                              // 8 MB
    unsigned int* binned = (unsigned int*)(ws + (size_t)NQ * DQ * 2);       // 4 MB
    unsigned short* bucket = (unsigned short*)(binned + (size_t)NBLK_P * EPB); // 5.25 MB
    unsigned short* Wt = bucket + (size_t)NQ * DEG_STRIDE;                  // 256 KB
    float* dinv = (float*)(Wt + 2 * DQ * DQ);                               // 64 KB
    int* cnt = (int*)(dinv + NQ);                                           // 64 KB
    int* cntT = cnt + NQ;                                                   // 256 KB
    int* offT = cntT + NBLK_P * NBINS;                                      // 256 KB

    const int* src = ei;
    const int* tgt = ei + EQ;

    k_wt_part<<<512, 256, 0, stream>>>(W, Wt, src, tgt, cntT, offT, binned);
    k_gemm_bucket<<<512, 256, 0, stream>>>(X, Wt, xwb, cntT, offT, binned,
                                           bucket, cnt, dinv);
    k_agg_scores<<<BQ, 512, 0, stream>>>((const unsigned int*)xwb, cnt, bucket,
                                         dinv, bias, out,
                                         out + (size_t)NQ * DQ);
}